// Round 1
// baseline (112.403 us; speedup 1.0000x reference)
//
#include <hip/hip_runtime.h>
#include <hip/hip_bf16.h>

typedef __bf16 bf16x8 __attribute__((ext_vector_type(8)));
typedef __bf16 bf16x4 __attribute__((ext_vector_type(4)));
typedef float f32x4 __attribute__((ext_vector_type(4)));

#define MFMA16(a,b,c) __builtin_amdgcn_mfma_f32_16x16x32_bf16(a, b, c, 0, 0, 0)

// ---------------- prep: f32 -> bf16 convert ----------------
__global__ __launch_bounds__(256) void cvt_f32_bf16(const float* __restrict__ in,
                                                    __bf16* __restrict__ out, int n) {
  int i = (blockIdx.x * 256 + threadIdx.x) * 4;
  if (i >= n) return;
  float4 v = *reinterpret_cast<const float4*>(in + i);
  bf16x4 o;
  o[0] = (__bf16)v.x; o[1] = (__bf16)v.y; o[2] = (__bf16)v.z; o[3] = (__bf16)v.w;
  *reinterpret_cast<bf16x4*>(out + i) = o;
}

// ---------------- prep: transpose + convert (out[c][r] = in[r][c]) ----------------
__global__ __launch_bounds__(256) void transpose_cvt(const float* __restrict__ in,
                                                     __bf16* __restrict__ out, int R, int C) {
  __shared__ float t[64][65];
  const int tilesC = C >> 6;
  const int tc = blockIdx.x % tilesC, tr = blockIdx.x / tilesC;
  const int r0 = tr << 6, c0 = tc << 6;
  const int tid = threadIdx.x;
  const int ri = tid >> 2, cq = (tid & 3) << 4;
#pragma unroll
  for (int e = 0; e < 16; e += 4) {
    float4 v = *reinterpret_cast<const float4*>(&in[(size_t)(r0 + ri) * C + c0 + cq + e]);
    t[ri][cq + e]     = v.x;
    t[ri][cq + e + 1] = v.y;
    t[ri][cq + e + 2] = v.z;
    t[ri][cq + e + 3] = v.w;
  }
  __syncthreads();
  const int co = tid >> 2, rq = (tid & 3) << 4;
  __attribute__((aligned(16))) __bf16 buf[16];
#pragma unroll
  for (int e = 0; e < 16; e++) buf[e] = (__bf16)t[rq + e][co];
  *reinterpret_cast<bf16x8*>(&out[(size_t)(c0 + co) * R + r0 + rq])     = *reinterpret_cast<bf16x8*>(&buf[0]);
  *reinterpret_cast<bf16x8*>(&out[(size_t)(c0 + co) * R + r0 + rq + 8]) = *reinterpret_cast<bf16x8*>(&buf[8]);
}

// ---------------- GEMM: C[M][N] = A[M][K] * Bt[N][K]^T  (bf16 in, OT out) ----------------
template <typename OT>
__global__ __launch_bounds__(256) void gemm_bt(const __bf16* __restrict__ A,
                                               const __bf16* __restrict__ Bt,
                                               OT* __restrict__ C, int M, int N, int K) {
  __shared__ __bf16 As[128][72];
  __shared__ __bf16 Bs[128][72];
  const int tid = threadIdx.x;
  const int wave = tid >> 6, lane = tid & 63;
  const int c = lane & 15, q4 = lane >> 4;
  const int bm = blockIdx.y << 7, bn = blockIdx.x << 7;
  const int wm = (wave >> 1) << 6, wn = (wave & 1) << 6;
  f32x4 acc[4][4];
#pragma unroll
  for (int m = 0; m < 4; m++)
#pragma unroll
    for (int n = 0; n < 4; n++)
#pragma unroll
      for (int e = 0; e < 4; e++) acc[m][n][e] = 0.f;

  const int srow = tid >> 1, scol = (tid & 1) << 5;
  for (int k0 = 0; k0 < K; k0 += 64) {
    __syncthreads();
    const __bf16* ag = A + (size_t)(bm + srow) * K + k0 + scol;
    const __bf16* bg = Bt + (size_t)(bn + srow) * K + k0 + scol;
    bf16x8 av[4], bv[4];
#pragma unroll
    for (int r = 0; r < 4; r++) av[r] = *reinterpret_cast<const bf16x8*>(ag + r * 8);
#pragma unroll
    for (int r = 0; r < 4; r++) bv[r] = *reinterpret_cast<const bf16x8*>(bg + r * 8);
#pragma unroll
    for (int r = 0; r < 4; r++) *reinterpret_cast<bf16x8*>(&As[srow][scol + r * 8]) = av[r];
#pragma unroll
    for (int r = 0; r < 4; r++) *reinterpret_cast<bf16x8*>(&Bs[srow][scol + r * 8]) = bv[r];
    __syncthreads();
#pragma unroll
    for (int ks = 0; ks < 2; ks++) {
      const int kk = ks * 32 + q4 * 8;
      bf16x8 af[4], bfv[4];
#pragma unroll
      for (int m = 0; m < 4; m++) af[m] = *reinterpret_cast<const bf16x8*>(&As[wm + m * 16 + c][kk]);
#pragma unroll
      for (int n = 0; n < 4; n++) bfv[n] = *reinterpret_cast<const bf16x8*>(&Bs[wn + n * 16 + c][kk]);
#pragma unroll
      for (int m = 0; m < 4; m++)
#pragma unroll
        for (int n = 0; n < 4; n++) acc[m][n] = MFMA16(af[m], bfv[n], acc[m][n]);
    }
  }
#pragma unroll
  for (int m = 0; m < 4; m++)
#pragma unroll
    for (int n = 0; n < 4; n++)
#pragma unroll
      for (int r2 = 0; r2 < 4; r2++) {
        const int row = bm + wm + m * 16 + q4 * 4 + r2;
        const int col = bn + wn + n * 16 + c;
        C[(size_t)row * N + col] = (OT)acc[m][n][r2];
      }
}

// ---------------- attention: scores + softmax -> attn (f32, window entries only) -----------
// grid: (32 qtiles, 16 b*h); block 256 (4 waves). QKV bf16 [4096][1536].
__global__ __launch_bounds__(256) void attn_scores(const __bf16* __restrict__ QKV,
                                                   float* __restrict__ attn) {
  __shared__ __bf16 Qs[64][72];
  __shared__ __bf16 Ks[64][72];
  __shared__ float red[4][64];
  __shared__ float rowstat[64];
  const int qt = blockIdx.x, bh = blockIdx.y;
  const int b = bh >> 3, h = bh & 7;
  const int qi0 = qt << 6;
  const int tid = threadIdx.x;
  const int wave = tid >> 6, lane = tid & 63;
  const int c = lane & 15, q4 = lane >> 4;

  {  // stage Q tile (64x64)
    const int r = tid >> 2, qq = (tid & 3) << 4;
    const __bf16* src = QKV + (size_t)(b * 2048 + qi0 + r) * 1536 + h * 64 + qq;
    bf16x8 v0 = *reinterpret_cast<const bf16x8*>(src);
    bf16x8 v1 = *reinterpret_cast<const bf16x8*>(src + 8);
    *reinterpret_cast<bf16x8*>(&Qs[r][qq]) = v0;
    *reinterpret_cast<bf16x8*>(&Qs[r][qq + 8]) = v1;
  }

  f32x4 acc[5][4];
#pragma unroll
  for (int t = 0; t < 5; t++)
#pragma unroll
    for (int m = 0; m < 4; m++)
#pragma unroll
      for (int e = 0; e < 4; e++) acc[t][m][e] = 0.f;

#pragma unroll
  for (int t = 0; t < 5; t++) {
    const int jt0 = (qt - 4 + t) << 6;
    if (jt0 < 0) continue;  // block-uniform
    __syncthreads();
    {  // stage K tile (64x64)
      const int r = tid >> 2, qq = (tid & 3) << 4;
      const __bf16* src = QKV + (size_t)(b * 2048 + jt0 + r) * 1536 + 512 + h * 64 + qq;
      bf16x8 v0 = *reinterpret_cast<const bf16x8*>(src);
      bf16x8 v1 = *reinterpret_cast<const bf16x8*>(src + 8);
      *reinterpret_cast<bf16x8*>(&Ks[r][qq]) = v0;
      *reinterpret_cast<bf16x8*>(&Ks[r][qq + 8]) = v1;
    }
    __syncthreads();
#pragma unroll
    for (int ks = 0; ks < 2; ks++) {
      const int kk = ks * 32 + q4 * 8;
      bf16x8 bfr = *reinterpret_cast<const bf16x8*>(&Ks[wave * 16 + c][kk]);
#pragma unroll
      for (int m = 0; m < 4; m++) {
        bf16x8 afr = *reinterpret_cast<const bf16x8*>(&Qs[m * 16 + c][kk]);
        acc[t][m] = MFMA16(afr, bfr, acc[t][m]);
      }
    }
  }

  // mask + scale in place
  const float scale = 0.125f;
#pragma unroll
  for (int t = 0; t < 5; t++) {
    const int jb = ((qt - 4 + t) << 6) + wave * 16 + c;
#pragma unroll
    for (int m = 0; m < 4; m++)
#pragma unroll
      for (int r2 = 0; r2 < 4; r2++) {
        const int ig = qi0 + m * 16 + q4 * 4 + r2;
        const bool valid = (jb >= 0) && (jb <= ig) && (jb >= ig - 255);
        acc[t][m][r2] = valid ? acc[t][m][r2] * scale : -1e30f;
      }
  }

  // row max: per-lane over t, shuffle over c (low 4 lane bits), cross-wave via LDS
  float pm[16];
#pragma unroll
  for (int m = 0; m < 4; m++)
#pragma unroll
    for (int r2 = 0; r2 < 4; r2++) {
      float v = acc[0][m][r2];
#pragma unroll
      for (int t = 1; t < 5; t++) v = fmaxf(v, acc[t][m][r2]);
      pm[m * 4 + r2] = v;
    }
#pragma unroll
  for (int off = 8; off >= 1; off >>= 1)
#pragma unroll
    for (int i = 0; i < 16; i++) pm[i] = fmaxf(pm[i], __shfl_xor(pm[i], off, 64));
  if (c == 0) {
#pragma unroll
    for (int m = 0; m < 4; m++)
#pragma unroll
      for (int r2 = 0; r2 < 4; r2++) red[wave][m * 16 + q4 * 4 + r2] = pm[m * 4 + r2];
  }
  __syncthreads();
  if (tid < 64)
    rowstat[tid] = fmaxf(fmaxf(red[0][tid], red[1][tid]), fmaxf(red[2][tid], red[3][tid]));
  __syncthreads();

  float rmax[16], ps[16];
#pragma unroll
  for (int m = 0; m < 4; m++)
#pragma unroll
    for (int r2 = 0; r2 < 4; r2++) {
      rmax[m * 4 + r2] = rowstat[m * 16 + q4 * 4 + r2];
      ps[m * 4 + r2] = 0.f;
    }
#pragma unroll
  for (int t = 0; t < 5; t++)
#pragma unroll
    for (int m = 0; m < 4; m++)
#pragma unroll
      for (int r2 = 0; r2 < 4; r2++) {
        float p = __expf(acc[t][m][r2] - rmax[m * 4 + r2]);
        acc[t][m][r2] = p;
        ps[m * 4 + r2] += p;
      }
#pragma unroll
  for (int off = 8; off >= 1; off >>= 1)
#pragma unroll
    for (int i = 0; i < 16; i++) ps[i] += __shfl_xor(ps[i], off, 64);
  if (c == 0) {
#pragma unroll
    for (int m = 0; m < 4; m++)
#pragma unroll
      for (int r2 = 0; r2 < 4; r2++) red[wave][m * 16 + q4 * 4 + r2] = ps[m * 4 + r2];
  }
  __syncthreads();
  if (tid < 64) rowstat[tid] = red[0][tid] + red[1][tid] + red[2][tid] + red[3][tid];
  __syncthreads();

  float* arow = attn + ((size_t)bh << 22);
#pragma unroll
  for (int m = 0; m < 4; m++)
#pragma unroll
    for (int r2 = 0; r2 < 4; r2++) {
      const int iloc = m * 16 + q4 * 4 + r2;
      const float rinv = 1.0f / rowstat[iloc];
      const int ig = qi0 + iloc;
#pragma unroll
      for (int t = 0; t < 5; t++) {
        const int jb = ((qt - 4 + t) << 6) + wave * 16 + c;
        if (jb >= 0 && jb <= ig && jb >= ig - 255)
          arow[(size_t)ig * 2048 + jb] = acc[t][m][r2] * rinv;
      }
    }
}

// ---------------- attention: out = P @ V  -> AO bf16 [4096][512] ----------------
__global__ __launch_bounds__(256) void attn_pv(const __bf16* __restrict__ QKV,
                                               const float* __restrict__ attn,
                                               __bf16* __restrict__ AO) {
  __shared__ __bf16 Vt[64][72];  // Vt[d][j]
  const int qt = blockIdx.x, bh = blockIdx.y;
  const int b = bh >> 3, h = bh & 7;
  const int qi0 = qt << 6;
  const int tid = threadIdx.x, wave = tid >> 6, lane = tid & 63;
  const int c = lane & 15, q4 = lane >> 4;
  f32x4 acc[4];
#pragma unroll
  for (int n = 0; n < 4; n++)
#pragma unroll
    for (int e = 0; e < 4; e++) acc[n][e] = 0.f;

  const float* prow = attn + ((size_t)bh << 22) + (size_t)(qi0 + wave * 16 + c) * 2048;
#pragma unroll
  for (int t = 0; t < 5; t++) {
    const int jt0 = (qt - 4 + t) << 6;
    if (jt0 < 0) continue;  // block-uniform
    __syncthreads();
    {  // stage V tile transposed
      const int j = tid >> 2, dq = tid & 3;
#pragma unroll
      for (int r = 0; r < 2; r++) {
        const int d0 = (dq + r * 4) << 3;
        bf16x8 v = *reinterpret_cast<const bf16x8*>(
            QKV + (size_t)(b * 2048 + jt0 + j) * 1536 + 1024 + h * 64 + d0);
#pragma unroll
        for (int e = 0; e < 8; e++) Vt[d0 + e][j] = v[e];
      }
    }
    __syncthreads();
#pragma unroll
    for (int ks = 0; ks < 2; ks++) {
      const int kk = ks * 32 + q4 * 8;
      f32x4 p0 = *reinterpret_cast<const f32x4*>(prow + jt0 + kk);
      f32x4 p1 = *reinterpret_cast<const f32x4*>(prow + jt0 + kk + 4);
      bf16x8 af;
      af[0] = (__bf16)p0[0]; af[1] = (__bf16)p0[1]; af[2] = (__bf16)p0[2]; af[3] = (__bf16)p0[3];
      af[4] = (__bf16)p1[0]; af[5] = (__bf16)p1[1]; af[6] = (__bf16)p1[2]; af[7] = (__bf16)p1[3];
#pragma unroll
      for (int n = 0; n < 4; n++) {
        bf16x8 bfr = *reinterpret_cast<const bf16x8*>(&Vt[n * 16 + c][kk]);
        acc[n] = MFMA16(af, bfr, acc[n]);
      }
    }
  }
#pragma unroll
  for (int n = 0; n < 4; n++)
#pragma unroll
    for (int r2 = 0; r2 < 4; r2++) {
      const int i = qi0 + wave * 16 + q4 * 4 + r2;
      const int d = n * 16 + c;
      AO[(size_t)(b * 2048 + i) * 512 + h * 64 + d] = (__bf16)acc[n][r2];
    }
}

// ---------------- launch ----------------
extern "C" void kernel_launch(void* const* d_in, const int* in_sizes, int n_in,
                              void* d_out, int out_size, void* d_ws, size_t ws_size,
                              hipStream_t stream) {
  const float* x = (const float*)d_in[0];      // (2,2048,512)
  const float* Wqkv = (const float*)d_in[1];   // (512,1536)
  const float* Wout = (const float*)d_in[2];   // (512,512)
  float* out = (float*)d_out;                  // (2,2048,512) f32
  float* attn = out + (size_t)2 * 2048 * 512;  // (2,8,2048,2048) f32

  char* ws = (char*)d_ws;
  __bf16* Xb   = (__bf16*)(ws);                                        // 4 MiB
  __bf16* Wqt  = (__bf16*)(ws + 4194304);                              // 1.5 MiB  [1536][512]
  __bf16* Wot  = (__bf16*)(ws + 4194304 + 1572864);                    // 0.5 MiB  [512][512]
  __bf16* QKVb = (__bf16*)(ws + 4194304 + 1572864 + 524288);           // 12 MiB   [4096][1536]
  __bf16* AOb  = (__bf16*)(ws + 4194304 + 1572864 + 524288 + 12582912);// 4 MiB    [4096][512]

  // zero the whole output (attn masked entries are exactly 0 in the reference)
  hipMemsetAsync(d_out, 0, (size_t)out_size * sizeof(float), stream);

  cvt_f32_bf16<<<2048, 256, 0, stream>>>(x, Xb, 2 * 2048 * 512);
  transpose_cvt<<<192, 256, 0, stream>>>(Wqkv, Wqt, 512, 1536);
  transpose_cvt<<<64, 256, 0, stream>>>(Wout, Wot, 512, 512);

  // QKV = Xb @ Wqkv  (4096 x 1536)
  gemm_bt<__bf16><<<dim3(12, 32), 256, 0, stream>>>(Xb, Wqt, QKVb, 4096, 1536, 512);

  attn_scores<<<dim3(32, 16), 256, 0, stream>>>(QKVb, attn);
  attn_pv<<<dim3(32, 16), 256, 0, stream>>>(QKVb, attn, AOb);

  // out = AO @ Wout  (4096 x 512)
  gemm_bt<float><<<dim3(4, 32), 256, 0, stream>>>(AOb, Wot, out, 4096, 512, 512);
}

// Round 2
// 100.330 us; speedup vs baseline: 1.1203x; 1.1203x over previous
//
#include <hip/hip_runtime.h>
#include <hip/hip_bf16.h>

typedef __bf16 bf16x8 __attribute__((ext_vector_type(8)));
typedef __bf16 bf16x4 __attribute__((ext_vector_type(4)));
typedef float f32x4 __attribute__((ext_vector_type(4)));

#define MFMA16(a,b,c) __builtin_amdgcn_mfma_f32_16x16x32_bf16(a, b, c, 0, 0, 0)

// ---------------- prep: f32 -> bf16 convert ----------------
__global__ __launch_bounds__(256) void cvt_f32_bf16(const float* __restrict__ in,
                                                    __bf16* __restrict__ out, int n) {
  int i = (blockIdx.x * 256 + threadIdx.x) * 4;
  if (i >= n) return;
  float4 v = *reinterpret_cast<const float4*>(in + i);
  bf16x4 o;
  o[0] = (__bf16)v.x; o[1] = (__bf16)v.y; o[2] = (__bf16)v.z; o[3] = (__bf16)v.w;
  *reinterpret_cast<bf16x4*>(out + i) = o;
}

// ---------------- prep: transpose + convert (out[c][r] = in[r][c]) ----------------
__global__ __launch_bounds__(256) void transpose_cvt(const float* __restrict__ in,
                                                     __bf16* __restrict__ out, int R, int C) {
  __shared__ float t[64][65];
  const int tilesC = C >> 6;
  const int tc = blockIdx.x % tilesC, tr = blockIdx.x / tilesC;
  const int r0 = tr << 6, c0 = tc << 6;
  const int tid = threadIdx.x;
  const int ri = tid >> 2, cq = (tid & 3) << 4;
#pragma unroll
  for (int e = 0; e < 16; e += 4) {
    float4 v = *reinterpret_cast<const float4*>(&in[(size_t)(r0 + ri) * C + c0 + cq + e]);
    t[ri][cq + e]     = v.x;
    t[ri][cq + e + 1] = v.y;
    t[ri][cq + e + 2] = v.z;
    t[ri][cq + e + 3] = v.w;
  }
  __syncthreads();
  const int co = tid >> 2, rq = (tid & 3) << 4;
  __attribute__((aligned(16))) __bf16 buf[16];
#pragma unroll
  for (int e = 0; e < 16; e++) buf[e] = (__bf16)t[rq + e][co];
  *reinterpret_cast<bf16x8*>(&out[(size_t)(c0 + co) * R + r0 + rq])     = *reinterpret_cast<bf16x8*>(&buf[0]);
  *reinterpret_cast<bf16x8*>(&out[(size_t)(c0 + co) * R + r0 + rq + 8]) = *reinterpret_cast<bf16x8*>(&buf[8]);
}

// ---------------- GEMM: C[M][N] = A[M][K] * Bt[N][K]^T  (bf16 in, OT out) ----------------
template <typename OT>
__global__ __launch_bounds__(256) void gemm_bt(const __bf16* __restrict__ A,
                                               const __bf16* __restrict__ Bt,
                                               OT* __restrict__ C, int M, int N, int K) {
  __shared__ __bf16 As[128][72];
  __shared__ __bf16 Bs[128][72];
  const int tid = threadIdx.x;
  const int wave = tid >> 6, lane = tid & 63;
  const int c = lane & 15, q4 = lane >> 4;
  const int bm = blockIdx.y << 7, bn = blockIdx.x << 7;
  const int wm = (wave >> 1) << 6, wn = (wave & 1) << 6;
  f32x4 acc[4][4];
#pragma unroll
  for (int m = 0; m < 4; m++)
#pragma unroll
    for (int n = 0; n < 4; n++)
#pragma unroll
      for (int e = 0; e < 4; e++) acc[m][n][e] = 0.f;

  const int srow = tid >> 1, scol = (tid & 1) << 5;
  for (int k0 = 0; k0 < K; k0 += 64) {
    __syncthreads();
    const __bf16* ag = A + (size_t)(bm + srow) * K + k0 + scol;
    const __bf16* bg = Bt + (size_t)(bn + srow) * K + k0 + scol;
    bf16x8 av[4], bv[4];
#pragma unroll
    for (int r = 0; r < 4; r++) av[r] = *reinterpret_cast<const bf16x8*>(ag + r * 8);
#pragma unroll
    for (int r = 0; r < 4; r++) bv[r] = *reinterpret_cast<const bf16x8*>(bg + r * 8);
#pragma unroll
    for (int r = 0; r < 4; r++) *reinterpret_cast<bf16x8*>(&As[srow][scol + r * 8]) = av[r];
#pragma unroll
    for (int r = 0; r < 4; r++) *reinterpret_cast<bf16x8*>(&Bs[srow][scol + r * 8]) = bv[r];
    __syncthreads();
#pragma unroll
    for (int ks = 0; ks < 2; ks++) {
      const int kk = ks * 32 + q4 * 8;
      bf16x8 af[4], bfv[4];
#pragma unroll
      for (int m = 0; m < 4; m++) af[m] = *reinterpret_cast<const bf16x8*>(&As[wm + m * 16 + c][kk]);
#pragma unroll
      for (int n = 0; n < 4; n++) bfv[n] = *reinterpret_cast<const bf16x8*>(&Bs[wn + n * 16 + c][kk]);
#pragma unroll
      for (int m = 0; m < 4; m++)
#pragma unroll
        for (int n = 0; n < 4; n++) acc[m][n] = MFMA16(af[m], bfv[n], acc[m][n]);
    }
  }
#pragma unroll
  for (int m = 0; m < 4; m++)
#pragma unroll
    for (int n = 0; n < 4; n++)
#pragma unroll
      for (int r2 = 0; r2 < 4; r2++) {
        const int row = bm + wm + m * 16 + q4 * 4 + r2;
        const int col = bn + wn + n * 16 + c;
        C[(size_t)row * N + col] = (OT)acc[m][n][r2];
      }
}

// -------- fused attention: scores + softmax + attn materialization + PV --------
// grid: (32 qtiles, 16 b*h); block 256 (4 waves). QKV bf16 [4096][1536].
__global__ __launch_bounds__(256) void attn_fused(const __bf16* __restrict__ QKV,
                                                  float* __restrict__ attn,
                                                  __bf16* __restrict__ AO) {
  __shared__ __bf16 Qs[64][72];
  __shared__ __bf16 Ks[64][72];  // reused as Vt[d][j] in PV phase
  __shared__ __bf16 Ps[64][72];  // P tile (bf16) for PV A-fragments
  __shared__ float red[4][64];
  __shared__ float rowstat[64];
  const int qt = blockIdx.x, bh = blockIdx.y;
  const int b = bh >> 3, h = bh & 7;
  const int qi0 = qt << 6;
  const int tid = threadIdx.x;
  const int wave = tid >> 6, lane = tid & 63;
  const int c = lane & 15, q4 = lane >> 4;

  {  // stage Q tile (64x64)
    const int r = tid >> 2, qq = (tid & 3) << 4;
    const __bf16* src = QKV + (size_t)(b * 2048 + qi0 + r) * 1536 + h * 64 + qq;
    bf16x8 v0 = *reinterpret_cast<const bf16x8*>(src);
    bf16x8 v1 = *reinterpret_cast<const bf16x8*>(src + 8);
    *reinterpret_cast<bf16x8*>(&Qs[r][qq]) = v0;
    *reinterpret_cast<bf16x8*>(&Qs[r][qq + 8]) = v1;
  }

  f32x4 acc[5][4];
#pragma unroll
  for (int t = 0; t < 5; t++)
#pragma unroll
    for (int m = 0; m < 4; m++)
#pragma unroll
      for (int e = 0; e < 4; e++) acc[t][m][e] = 0.f;

#pragma unroll
  for (int t = 0; t < 5; t++) {
    const int jt0 = (qt - 4 + t) << 6;
    if (jt0 < 0) continue;  // block-uniform
    __syncthreads();
    {  // stage K tile (64x64)
      const int r = tid >> 2, qq = (tid & 3) << 4;
      const __bf16* src = QKV + (size_t)(b * 2048 + jt0 + r) * 1536 + 512 + h * 64 + qq;
      bf16x8 v0 = *reinterpret_cast<const bf16x8*>(src);
      bf16x8 v1 = *reinterpret_cast<const bf16x8*>(src + 8);
      *reinterpret_cast<bf16x8*>(&Ks[r][qq]) = v0;
      *reinterpret_cast<bf16x8*>(&Ks[r][qq + 8]) = v1;
    }
    __syncthreads();
#pragma unroll
    for (int ks = 0; ks < 2; ks++) {
      const int kk = ks * 32 + q4 * 8;
      bf16x8 bfr = *reinterpret_cast<const bf16x8*>(&Ks[wave * 16 + c][kk]);
#pragma unroll
      for (int m = 0; m < 4; m++) {
        bf16x8 afr = *reinterpret_cast<const bf16x8*>(&Qs[m * 16 + c][kk]);
        acc[t][m] = MFMA16(afr, bfr, acc[t][m]);
      }
    }
  }

  // mask + scale in place
  const float scale = 0.125f;
#pragma unroll
  for (int t = 0; t < 5; t++) {
    const int jb = ((qt - 4 + t) << 6) + wave * 16 + c;
#pragma unroll
    for (int m = 0; m < 4; m++)
#pragma unroll
      for (int r2 = 0; r2 < 4; r2++) {
        const int ig = qi0 + m * 16 + q4 * 4 + r2;
        const bool valid = (jb >= 0) && (jb <= ig) && (jb >= ig - 255);
        acc[t][m][r2] = valid ? acc[t][m][r2] * scale : -1e30f;
      }
  }

  // row max: per-lane over t, shuffle over c (low 4 lane bits), cross-wave via LDS
  float pm[16];
#pragma unroll
  for (int m = 0; m < 4; m++)
#pragma unroll
    for (int r2 = 0; r2 < 4; r2++) {
      float v = acc[0][m][r2];
#pragma unroll
      for (int t = 1; t < 5; t++) v = fmaxf(v, acc[t][m][r2]);
      pm[m * 4 + r2] = v;
    }
#pragma unroll
  for (int off = 8; off >= 1; off >>= 1)
#pragma unroll
    for (int i = 0; i < 16; i++) pm[i] = fmaxf(pm[i], __shfl_xor(pm[i], off, 64));
  if (c == 0) {
#pragma unroll
    for (int m = 0; m < 4; m++)
#pragma unroll
      for (int r2 = 0; r2 < 4; r2++) red[wave][m * 16 + q4 * 4 + r2] = pm[m * 4 + r2];
  }
  __syncthreads();
  if (tid < 64)
    rowstat[tid] = fmaxf(fmaxf(red[0][tid], red[1][tid]), fmaxf(red[2][tid], red[3][tid]));
  __syncthreads();

  float rmax[16], ps[16];
#pragma unroll
  for (int m = 0; m < 4; m++)
#pragma unroll
    for (int r2 = 0; r2 < 4; r2++) {
      rmax[m * 4 + r2] = rowstat[m * 16 + q4 * 4 + r2];
      ps[m * 4 + r2] = 0.f;
    }
#pragma unroll
  for (int t = 0; t < 5; t++)
#pragma unroll
    for (int m = 0; m < 4; m++)
#pragma unroll
      for (int r2 = 0; r2 < 4; r2++) {
        float p = __expf(acc[t][m][r2] - rmax[m * 4 + r2]);
        acc[t][m][r2] = p;
        ps[m * 4 + r2] += p;
      }
#pragma unroll
  for (int off = 8; off >= 1; off >>= 1)
#pragma unroll
    for (int i = 0; i < 16; i++) ps[i] += __shfl_xor(ps[i], off, 64);
  if (c == 0) {
#pragma unroll
    for (int m = 0; m < 4; m++)
#pragma unroll
      for (int r2 = 0; r2 < 4; r2++) red[wave][m * 16 + q4 * 4 + r2] = ps[m * 4 + r2];
  }
  __syncthreads();
  if (tid < 64) rowstat[tid] = red[0][tid] + red[1][tid] + red[2][tid] + red[3][tid];
  __syncthreads();

  // normalize acc in place -> final attention probabilities (masked entries are exactly 0)
#pragma unroll
  for (int m = 0; m < 4; m++)
#pragma unroll
    for (int r2 = 0; r2 < 4; r2++) {
      const float rinv = 1.0f / rowstat[m * 16 + q4 * 4 + r2];
#pragma unroll
      for (int t = 0; t < 5; t++) acc[t][m][r2] *= rinv;
    }

  // ---------------- PV phase: O = P @ V (LDS bounce for P) ----------------
  f32x4 o[4];
#pragma unroll
  for (int n = 0; n < 4; n++)
#pragma unroll
    for (int e = 0; e < 4; e++) o[n][e] = 0.f;

#pragma unroll
  for (int t = 0; t < 5; t++) {
    const int jt0 = (qt - 4 + t) << 6;
    if (jt0 < 0) continue;  // block-uniform
    __syncthreads();
    // P tile -> LDS (bf16), layout Ps[i][j]
#pragma unroll
    for (int m = 0; m < 4; m++)
#pragma unroll
      for (int r2 = 0; r2 < 4; r2++)
        Ps[m * 16 + q4 * 4 + r2][wave * 16 + c] = (__bf16)acc[t][m][r2];
    // stage V tile transposed: Vt[d][j] in Ks
    {
      const int j = tid >> 2, dq = tid & 3;
#pragma unroll
      for (int r = 0; r < 2; r++) {
        const int d0 = (dq + r * 4) << 3;
        bf16x8 v = *reinterpret_cast<const bf16x8*>(
            QKV + (size_t)(b * 2048 + jt0 + j) * 1536 + 1024 + h * 64 + d0);
#pragma unroll
        for (int e = 0; e < 8; e++) Ks[d0 + e][j] = v[e];
      }
    }
    __syncthreads();
#pragma unroll
    for (int ks = 0; ks < 2; ks++) {
      const int kk = ks * 32 + q4 * 8;
      bf16x8 af = *reinterpret_cast<const bf16x8*>(&Ps[wave * 16 + c][kk]);
#pragma unroll
      for (int n = 0; n < 4; n++) {
        bf16x8 bfr = *reinterpret_cast<const bf16x8*>(&Ks[n * 16 + c][kk]);
        o[n] = MFMA16(af, bfr, o[n]);
      }
    }
  }

  // ---------------- global stores (after last barrier; no vmcnt-drain serialization) -----
  // AO
#pragma unroll
  for (int n = 0; n < 4; n++)
#pragma unroll
    for (int r2 = 0; r2 < 4; r2++) {
      const int i = qi0 + wave * 16 + q4 * 4 + r2;
      const int d = n * 16 + c;
      AO[(size_t)(b * 2048 + i) * 512 + h * 64 + d] = (__bf16)o[n][r2];
    }

  float* arow = attn + ((size_t)bh << 22);
  // band stores: unconditional (masked in-band entries are 0)
#pragma unroll
  for (int t = 0; t < 5; t++) {
    const int jt0 = (qt - 4 + t) << 6;
    if (jt0 < 0) continue;
    const int jb = jt0 + wave * 16 + c;
#pragma unroll
    for (int m = 0; m < 4; m++)
#pragma unroll
      for (int r2 = 0; r2 < 4; r2++) {
        const int ig = qi0 + m * 16 + q4 * 4 + r2;
        arow[(size_t)ig * 2048 + jb] = acc[t][m][r2];
      }
  }

  // zero-fill outside the band, coalesced float4
  const int bandLo = qt >= 4 ? ((qt - 4) << 6) : 0;
  const int bandHi = (qt + 1) << 6;
  const f32x4 z4 = {0.f, 0.f, 0.f, 0.f};
#pragma unroll 4
  for (int r = 0; r < 64; r++) {
    float* rp = arow + ((size_t)(qi0 + r) << 11);
#pragma unroll
    for (int pass = 0; pass < 2; pass++) {
      const int j = (pass << 10) + (tid << 2);
      if (j < bandLo || j >= bandHi)
        *reinterpret_cast<f32x4*>(rp + j) = z4;
    }
  }
}

// ---------------- launch ----------------
extern "C" void kernel_launch(void* const* d_in, const int* in_sizes, int n_in,
                              void* d_out, int out_size, void* d_ws, size_t ws_size,
                              hipStream_t stream) {
  const float* x = (const float*)d_in[0];      // (2,2048,512)
  const float* Wqkv = (const float*)d_in[1];   // (512,1536)
  const float* Wout = (const float*)d_in[2];   // (512,512)
  float* out = (float*)d_out;                  // (2,2048,512) f32
  float* attn = out + (size_t)2 * 2048 * 512;  // (2,8,2048,2048) f32

  char* ws = (char*)d_ws;
  __bf16* Xb   = (__bf16*)(ws);                                        // 4 MiB
  __bf16* Wqt  = (__bf16*)(ws + 4194304);                              // 1.5 MiB  [1536][512]
  __bf16* Wot  = (__bf16*)(ws + 4194304 + 1572864);                    // 0.5 MiB  [512][512]
  __bf16* QKVb = (__bf16*)(ws + 4194304 + 1572864 + 524288);           // 12 MiB   [4096][1536]
  __bf16* AOb  = (__bf16*)(ws + 4194304 + 1572864 + 524288 + 12582912);// 4 MiB    [4096][512]

  cvt_f32_bf16<<<2048, 256, 0, stream>>>(x, Xb, 2 * 2048 * 512);
  transpose_cvt<<<192, 256, 0, stream>>>(Wqkv, Wqt, 512, 1536);
  transpose_cvt<<<64, 256, 0, stream>>>(Wout, Wot, 512, 512);

  // QKV = Xb @ Wqkv  (4096 x 1536)
  gemm_bt<__bf16><<<dim3(12, 32), 256, 0, stream>>>(Xb, Wqt, QKVb, 4096, 1536, 512);

  attn_fused<<<dim3(32, 16), 256, 0, stream>>>(QKVb, attn, AOb);

  // out = AO @ Wout  (4096 x 512)
  gemm_bt<float><<<dim3(4, 32), 256, 0, stream>>>(AOb, Wot, out, 4096, 512, 512);
}